// Round 13
// baseline (18485.301 us; speedup 1.0000x reference)
//
#include <hip/hip_runtime.h>
#include <math.h>

#define TT 200
#define NDIM 1024
#define IDIM 128
#define ODIM 128
#define NB 256

// ws float offsets (state only; J/B/W used from natural inputs)
#define SG_OFF 0          // f32 Sg[2][256][1024] sigmoid(V)  (LLC-coherent)
#define TH_OFF 524288     // f32 Th[2][256][1024] tanh(V)     (LLC-coherent)
#define BAR_OFF 1048576   // u32 cnt[8][2] @ +0..15, u32 flg[8] @ +16..23

// d_out float offsets
#define VT_STRIDE 205824
#define ZT_BASE   52690944
#define OUTS_BASE 105381888

#define JSTR 1028   // 4KB row + 16B pad (16B-aligned rows, 4-way worst conflict)
#define BSTR 132

#define ALD(p) __hip_atomic_load((const double*)(p), __ATOMIC_RELAXED, \
                                 __HIP_MEMORY_SCOPE_AGENT)
#define AST(p, v) __hip_atomic_store((p), (v), __ATOMIC_RELAXED, \
                                     __HIP_MEMORY_SCOPE_AGENT)

// load 4 consecutive floats via two 8B agent-scope (LLC-direct) loads
__device__ __forceinline__ void ald4(const float* p, float& x, float& y,
                                     float& z, float& w) {
  union { double d; float f[2]; } u0, u1;
  u0.d = ALD(p);
  u1.d = ALD(p + 2);
  x = u0.f[0]; y = u0.f[1]; z = u1.f[0]; w = u1.f[1];
}

__global__ __launch_bounds__(256) void rsnn_prologue(float* __restrict__ ws,
                                                     float* __restrict__ out) {
  const int idx = blockIdx.x * 256 + threadIdx.x;   // 0..262143
  ws[SG_OFF + idx] = 0.5f;                          // sigmoid(0), parity 0
  ws[TH_OFF + idx] = 0.0f;                          // tanh(0),   parity 0
  const int b = idx >> 10, n = idx & 1023;
  out[(size_t)b * VT_STRIDE + n] = 0.0f;
  out[ZT_BASE + (size_t)b * VT_STRIDE + n] = 0.0f;
  if (idx < 32) ((unsigned*)(ws + BAR_OFF))[idx] = 0u;   // cnt[16] + flg[8]
}

// Persistent: 256 blocks (g=blk>>5: 32-batch group, nt=blk&31: 32-neuron tile)
// x 512 threads. J-slice + B-slice pinned in LDS for all 200 steps (L2 is never
// invalidated now -> J/W/B/X stay hot). sigma/tanh exchange is LLC-coherent via
// sc0sc1 atomic stores/loads => NO __threadfence (no L2 writeback/invalidate).
// Bit-exact R1 chains: k-chunks {0-287,288-575,576-863,864-1023+input},
// reduce ((p0+p1)+p2)+p3, verbatim epilogue. Per-group barrier = 32 blocks,
// relaxed atomics + step-parity counters.
__global__ __launch_bounds__(512, 1) void rsnn_persist(
    const float* __restrict__ inputs, const float* __restrict__ noise,
    const float* __restrict__ J, const float* __restrict__ Bm,
    const float* __restrict__ W,
    float* __restrict__ ws, float* __restrict__ out) {
  const int tid = threadIdx.x;
  const int g = blockIdx.x >> 5;        // 0..7 batch-group
  const int nt = blockIdx.x & 31;       // 0..31 neuron tile
  const int bbase = g << 5;
  const int n0 = nt << 5;

  float* Sg = ws + SG_OFF;
  float* Th = ws + TH_OFF;
  unsigned* barp = (unsigned*)(ws + BAR_OFF);
  unsigned* flg = barp + 16 + g;

  __shared__ float J_lds[32 * JSTR];    // 131.6 KB
  __shared__ float B_lds[32 * BSTR];    // 16.9 KB
  __shared__ float red2[4][32][4];      // 2 KB

  // one-time: stage J rows [n0,n0+32) and B rows into LDS (coalesced)
  {
    const int r = tid >> 4;             // 0..31
    const int c0 = (tid & 15) << 6;     // 0,64,...,960
    const float* src = J + (size_t)(n0 + r) * NDIM + c0;
    float* dst = J_lds + r * JSTR + c0;
#pragma unroll
    for (int j = 0; j < 16; ++j)
      *(float4*)(dst + (j << 2)) = *(const float4*)(src + (j << 2));
    if ((tid & 15) < 2) {
      const int i0 = (tid & 15) << 6;
      const float* bsrc = Bm + (size_t)(n0 + r) * IDIM + i0;
      float* bdst = B_lds + r * BSTR + i0;
#pragma unroll
      for (int j = 0; j < 16; ++j)
        *(float4*)(bdst + (j << 2)) = *(const float4*)(bsrc + (j << 2));
    }
  }
  __syncthreads();

  const int n_l = tid & 31;
  const int bh = tid >> 5;              // 0..15
  const int bA = bbase + bh, bB = bA + 16;
  const int ng = n0 + n_l;
  const float* Jrow = J_lds + n_l * JSTR;
  const float* Brow = B_lds + n_l * BSTR;

  float vA = 0.f, vB = 0.f;

  for (int s = 0; s <= TT; ++s) {
    if (s) {
      // ---- per-group barrier (32 blocks), fence-free ----
      // __syncthreads drains vmcnt per wave -> all sc0sc1 stores acked at LLC.
      __syncthreads();
      if (tid == 0) {
        unsigned* cnt = barp + (g << 1) + (s & 1);   // step-parity counter
        unsigned prev = __hip_atomic_fetch_add(cnt, 1u, __ATOMIC_RELAXED,
                                               __HIP_MEMORY_SCOPE_AGENT);
        if (prev == 31u) {
          __hip_atomic_store(cnt, 0u, __ATOMIC_RELAXED, __HIP_MEMORY_SCOPE_AGENT);
          __hip_atomic_store(flg, (unsigned)s, __ATOMIC_RELAXED,
                             __HIP_MEMORY_SCOPE_AGENT);
        } else {
          while (__hip_atomic_load(flg, __ATOMIC_RELAXED,
                                   __HIP_MEMORY_SCOPE_AGENT) < (unsigned)s)
            __builtin_amdgcn_s_sleep(1);
        }
      }
      __syncthreads();
    }

    if (s < TT) {
      const float* Sp = Sg + (size_t)(s & 1) * (NB * NDIM);
      const float* SA = Sp + (size_t)bA * NDIM;
      const float* SB = Sp + (size_t)bB * NDIM;
      float pA[4], pB[4];
#pragma unroll
      for (int q = 0; q < 3; ++q) {     // full unroll: static pA/pB indices
        float aA = 0.f, aB = 0.f;
        const int kb = q * 288;
#pragma unroll 8
        for (int g4 = 0; g4 < 72; ++g4) {
          const int k = kb + (g4 << 2);
          float sax, say, saz, saw, sbx, sby, sbz, sbw;
          ald4(SA + k, sax, say, saz, saw);
          ald4(SB + k, sbx, sby, sbz, sbw);
          const float4 jv = *(const float4*)(Jrow + k);
          aA = fmaf(sax, jv.x, aA); aA = fmaf(say, jv.y, aA);
          aA = fmaf(saz, jv.z, aA); aA = fmaf(saw, jv.w, aA);
          aB = fmaf(sbx, jv.x, aB); aB = fmaf(sby, jv.y, aB);
          aB = fmaf(sbz, jv.z, aB); aB = fmaf(sbw, jv.w, aB);
        }
        pA[q] = aA; pB[q] = aB;
      }
      {
        float aA = 0.f, aB = 0.f;
#pragma unroll 8
        for (int g4 = 0; g4 < 40; ++g4) {   // k = 864..1023
          const int k = 864 + (g4 << 2);
          float sax, say, saz, saw, sbx, sby, sbz, sbw;
          ald4(SA + k, sax, say, saz, saw);
          ald4(SB + k, sbx, sby, sbz, sbw);
          const float4 jv = *(const float4*)(Jrow + k);
          aA = fmaf(sax, jv.x, aA); aA = fmaf(say, jv.y, aA);
          aA = fmaf(saz, jv.z, aA); aA = fmaf(saw, jv.w, aA);
          aB = fmaf(sbx, jv.x, aB); aB = fmaf(sby, jv.y, aB);
          aB = fmaf(sbz, jv.z, aB); aB = fmaf(sbw, jv.w, aB);
        }
        const float* XA = inputs + ((size_t)bA * TT + s) * IDIM;
        const float* XB = inputs + ((size_t)bB * TT + s) * IDIM;
#pragma unroll 8
        for (int i4 = 0; i4 < 32; ++i4) {   // input proj appended (R1 order)
          const int i = i4 << 2;
          const float4 xa = *(const float4*)(XA + i);
          const float4 xb = *(const float4*)(XB + i);
          const float4 bv = *(const float4*)(Brow + i);
          aA = fmaf(xa.x, bv.x, aA); aA = fmaf(xa.y, bv.y, aA);
          aA = fmaf(xa.z, bv.z, aA); aA = fmaf(xa.w, bv.w, aA);
          aB = fmaf(xb.x, bv.x, aB); aB = fmaf(xb.y, bv.y, aB);
          aB = fmaf(xb.z, bv.z, aB); aB = fmaf(xb.w, bv.w, aB);
        }
        pA[3] = aA; pB[3] = aB;
      }
      const float sumA = ((pA[0] + pA[1]) + pA[2]) + pA[3];
      const float sumB = ((pB[0] + pB[1]) + pB[2]) + pB[3];

      const int p = (s + 1) & 1;
      float* Sgn = Sg + (size_t)p * (NB * NDIM);
      float* Thn = Th + (size_t)p * (NB * NDIM);
      // cell A epilogue (verbatim R1)
      {
        float vnew = 0.9f * vA + 0.1f * sumA;
        vA = vnew;
        out[(size_t)bA * VT_STRIDE + (size_t)(s + 1) * NDIM + ng] = vnew;
        float sgv = 1.0f / (1.0f + expf(-vnew));
        AST(&Sgn[(size_t)bA * NDIM + ng], sgv);
        AST(&Thn[(size_t)bA * NDIM + ng], tanhf(vnew));
        float zarg = (0.1f * (vnew - 0.4f)) / 0.4f;
        float zs = 1.0f / (1.0f + expf(-zarg));
        float u = noise[((size_t)bA * TT + s) * NDIM + ng];
        out[ZT_BASE + (size_t)bA * VT_STRIDE + (size_t)(s + 1) * NDIM + ng] =
            (zs > u) ? 1.0f : 0.0f;
      }
      // cell B epilogue
      {
        float vnew = 0.9f * vB + 0.1f * sumB;
        vB = vnew;
        out[(size_t)bB * VT_STRIDE + (size_t)(s + 1) * NDIM + ng] = vnew;
        float sgv = 1.0f / (1.0f + expf(-vnew));
        AST(&Sgn[(size_t)bB * NDIM + ng], sgv);
        AST(&Thn[(size_t)bB * NDIM + ng], tanhf(vnew));
        float zarg = (0.1f * (vnew - 0.4f)) / 0.4f;
        float zs = 1.0f / (1.0f + expf(-zarg));
        float u = noise[((size_t)bB * TT + s) * NDIM + ng];
        out[ZT_BASE + (size_t)bB * VT_STRIDE + (size_t)(s + 1) * NDIM + ng] =
            (zs > u) ? 1.0f : 0.0f;
      }
    }

    if (s >= 1) {
      // ---- outs partials for t = s-1 (Th is cross-block -> LLC loads)
      const float* Tp = Th + (size_t)(s & 1) * (NB * NDIM);
      const int kq = tid >> 7, rem = tid & 127;
      const int b_l = rem >> 2, o_l = rem & 3;
      const int ob = bbase + b_l;
      const int o = (nt << 2) + o_l;
      const float* trow = Tp + (size_t)ob * NDIM + (kq << 8);
      const float* wrow = W + (size_t)o * NDIM + (kq << 8);
      float acc = 0.f;
#pragma unroll 8
      for (int k4 = 0; k4 < 64; ++k4) {
        float tx, ty, tz, tw;
        ald4(trow + (k4 << 2), tx, ty, tz, tw);
        const float4 wv = *(const float4*)(wrow + (k4 << 2));
        acc = fmaf(tx, wv.x, acc);
        acc = fmaf(ty, wv.y, acc);
        acc = fmaf(tz, wv.z, acc);
        acc = fmaf(tw, wv.w, acc);
      }
      red2[kq][b_l][o_l] = acc;
    }
    __syncthreads();
    if (s >= 1 && tid < 128) {
      const int b_l = tid >> 2, o_l = tid & 3;
      float sum2 = ((red2[0][b_l][o_l] + red2[1][b_l][o_l]) +
                    red2[2][b_l][o_l]) + red2[3][b_l][o_l];
      const int ob = bbase + b_l;
      const int o = (nt << 2) + o_l;
      out[OUTS_BASE + ((size_t)ob * TT + (s - 1)) * ODIM + o] = sum2;
    }
  }
}

extern "C" void kernel_launch(void* const* d_in, const int* in_sizes, int n_in,
                              void* d_out, int out_size, void* d_ws, size_t ws_size,
                              hipStream_t stream) {
  const float* inputs = (const float*)d_in[0];  // (256,200,128)
  const float* noise  = (const float*)d_in[1];  // (256,200,1024)
  const float* J      = (const float*)d_in[2];  // (1024,1024)
  const float* Bm     = (const float*)d_in[3];  // (1024,128)
  const float* W      = (const float*)d_in[4];  // (128,1024)
  float* out = (float*)d_out;
  float* ws  = (float*)d_ws;

  rsnn_prologue<<<1024, 256, 0, stream>>>(ws, out);
  rsnn_persist<<<256, 512, 0, stream>>>(inputs, noise, J, Bm, W, ws, out);
}